// Round 11
// baseline (29.879 us; speedup 1.0000x reference)
//
#include <hip/hip_runtime.h>

// Flux_Kernels: 5-point stencil with Dirichlet BCs on all 4 sides.
// out[i,j] = D * ( s0*(nUp + nDown + nLeft + nRight) + 4*s1*u[i,j] )
// Off-grid neighbors -> dirichlet_val[{0,1,2,3}] for {i=0, i=NX-1, j=0, j=NY-1}.
//
// Round-11: TLP-vs-MSHR discriminator. Identical dataflow to R10 (two
// overlapping dword-aligned loads per row, cndmask edges, no DS ops,
// sched_barrier region fences) but ROWS=8 / grid=2048 / launch_bounds(256,8)
// -> 8 blocks/CU = 32 waves/CU (2x R10's 16). Five structures plateaued at
// ~26 us; if the limiter is insufficient in-flight bytes (waves x ~2 loads),
// doubling resident waves doubles in-flight depth -> ~22-24 us. If the
// limiter is the per-CU L1 outstanding-miss (MSHR) budget, this stays flat
// and the next test is LDS read-once staging. Amp cost: reads 1.125x->1.25x.

#define NX 4096
#define NY 4096
#define ROWS 8
#define PF 4                 // prefetch distance (slots in flight)
#define SLOTS (ROWS + 2)     // slot k holds grid row i0 + k - 1

typedef float float4v __attribute__((ext_vector_type(4)));
typedef float float4a __attribute__((ext_vector_type(4), aligned(4)));

__global__ __launch_bounds__(256, 8) void flux_stencil_kernel(
    const float* __restrict__ u,
    const float* __restrict__ D_eff,
    const float* __restrict__ dv,
    const float* __restrict__ st,
    float* __restrict__ out)
{
    const float D  = D_eff[0];
    const float s0 = st[0];
    const float s1 = st[1];
    const float k1 = D * s0;         // neighbor coefficient
    const float k4 = 4.0f * D * s1;  // center coefficient
    const float dvUp = dv[0], dvDn = dv[1], dvL = dv[2], dvR = dv[3];

    // XCD-aware bijective swizzle over 2048 blocks (XCD = hw%8):
    // x = hw&7 -> cg = x>>1 (column group 0..3), band = ((x&1)<<8) + (hw>>3).
    // Vertically-adjacent bands (same cg) are hw and hw+8 -> same XCD L2.
    const int hw   = blockIdx.x;
    const int x    = hw & 7;
    const int band = ((x & 1) << 8) + (hw >> 3);   // [0,512)
    const int cg   = x >> 1;                       // [0,4)
    const int w    = threadIdx.x >> 6;             // wave in block [0,4)
    const int lane = threadIdx.x & 63;
    const int j    = cg * 1024 + w * 256 + lane * 4;
    const int i0   = band * ROWS;

    const bool fL = (j == 0);
    const bool fR = (j + 4 == NY);
    const int  aO = fL ? 0 : -1;     // A-load col offset (clamped at left edge)
    const int  bO = fR ? 0 : 1;      // B-load col offset (clamped at right edge)
    const bool topEdge = (i0 == 0);
    const bool botEdge = (i0 + ROWS == NX);

    const float* base = u   + (size_t)i0 * NY + j;   // row i0, col j
    float*       outp = out + (size_t)i0 * NY + j;

    float4v A[SLOTS], B[SLOTS];      // raw overlapping loads per slot
    float4v cc[SLOTS];               // reconstructed 4-wide center values
    float   lf[SLOTS], rg[SLOTS];    // left/right neighbors per slot

    // ---- issue: slot k covers grid row (i0 + k - 1), clamped at grid ends ----
    #define ISSUE(k)                                                           \
    {                                                                          \
        int rr = (k) - 1;                                                      \
        if ((k) == 0 && topEdge)         rr = 0;        /* row -1 clamp */     \
        if ((k) == SLOTS - 1 && botEdge) rr = ROWS - 1; /* row NX clamp */     \
        const float* p = base + (ptrdiff_t)rr * NY;                            \
        A[k] = *reinterpret_cast<const float4a*>(p + aO);                      \
        B[k] = *reinterpret_cast<const float4a*>(p + bO);                      \
    }

    // ---- reconstruct slot k: cc, lf, rg from A/B with edge selects ----
    #define RECON(k)                                                           \
    {                                                                          \
        const float4v a = A[k], b = B[k];                                      \
        float4v c;                                                             \
        c.x = fL ? a.x : a.y;                                                  \
        c.y = fL ? a.y : a.z;                                                  \
        c.z = fL ? a.z : a.w;                                                  \
        c.w = fR ? b.w : b.z;                                                  \
        lf[k] = fL ? dvL : a.x;                                                \
        rg[k] = fR ? dvR : b.w;                                                \
        if ((k) == 0 && topEdge)         { c.x = dvUp; c.y = dvUp; c.z = dvUp; c.w = dvUp; } \
        if ((k) == SLOTS - 1 && botEdge) { c.x = dvDn; c.y = dvDn; c.z = dvDn; c.w = dvDn; } \
        cc[k] = c;                                                             \
    }

    // ---- compute + store center row (k-1) once cc[k] is available ----
    #define STORE(k)                                                           \
    {                                                                          \
        const float4v up = cc[(k) - 2], c = cc[(k) - 1], dn = cc[k];           \
        const float l = lf[(k) - 1], r = rg[(k) - 1];                          \
        float4v o;                                                             \
        o.x = k1 * (up.x + dn.x + l   + c.y) + k4 * c.x;                       \
        o.y = k1 * (up.y + dn.y + c.x + c.z) + k4 * c.y;                       \
        o.z = k1 * (up.z + dn.z + c.y + c.w) + k4 * c.z;                       \
        o.w = k1 * (up.w + dn.w + c.z + r  ) + k4 * c.w;                       \
        *reinterpret_cast<float4v*>(outp + (size_t)((k) - 2) * NY) = o;        \
    }

    // prologue: fill pipeline with slots 0..PF-1, then fence
    #pragma unroll
    for (int k = 0; k < PF; ++k) ISSUE(k)
    __builtin_amdgcn_sched_barrier(0);

    // steady state: each region = {issue slot k+PF} fence {consume slot k}
    #pragma unroll
    for (int k = 0; k < SLOTS; ++k) {
        if (k + PF < SLOTS) ISSUE(k + PF)
        __builtin_amdgcn_sched_barrier(0);   // loads above cannot sink below
        RECON(k)
        if (k >= 2) STORE(k)
        __builtin_amdgcn_sched_barrier(0);   // consumes cannot drift across regions
    }

    #undef ISSUE
    #undef RECON
    #undef STORE
}

extern "C" void kernel_launch(void* const* d_in, const int* in_sizes, int n_in,
                              void* d_out, int out_size, void* d_ws, size_t ws_size,
                              hipStream_t stream) {
    const float* u_main    = (const float*)d_in[0];
    // d_in[1] = u_coupled (unused)
    const float* D_eff     = (const float*)d_in[2];
    const float* dirichlet = (const float*)d_in[3];
    const float* stencil   = (const float*)d_in[4];
    // d_in[5] = t (unused)
    float* outp = (float*)d_out;

    // (4096/ROWS)=512 bands x 4 column-groups = 2048 blocks of 256 threads
    const int grid  = 2048;    // 8 blocks/CU, 32 waves/CU
    const int block = 256;

    flux_stencil_kernel<<<grid, block, 0, stream>>>(u_main, D_eff, dirichlet, stencil, outp);
}

// Round 12
// 24.529 us; speedup vs baseline: 1.2181x; 1.2181x over previous
//
#include <hip/hip_runtime.h>
#include <cstdint>

// Flux_Kernels: 5-point stencil with Dirichlet BCs on all 4 sides.
// out[i,j] = D * ( s0*(nUp + nDown + nLeft + nRight) + 4*s1*u[i,j] )
// Off-grid neighbors -> dirichlet_val[{0,1,2,3}] for {i=0, i=NX-1, j=0, j=NY-1}.
//
// Round-12: LDS-staged tiles via the global_load_lds DMA path. Every
// register-marched variant plateaued at ~4.0 TB/s HBM composite (R8/R10/R11)
// regardless of occupancy or pipelining: the VGPR-return read path never held
// more than ~2 loads in flight per wave. This kernel reads the input ONCE via
// async global->LDS DMA (no VGPR return, aligned dwordx4-only, amp 18/16),
// then computes entirely from LDS. One barrier per block; with 8 independent
// blocks/CU the barrier drain of one block is covered by the other seven
// (unlike GEMM's lockstep barrier stall). lft/rgt come from LDS halo columns
// -- the unaligned A/B double-read is gone.
//
// Tile: 16 rows x 256 cols per block (4096 blocks). LDS 18 rows x 264 floats
// (19 KB) -> 8 blocks/CU. XCD swizzle: XCD X owns bands [32X, 32X+32) -- a
// contiguous 512-row slab; vertical+horizontal halo re-reads stay in its L2.

#define NX 4096
#define NY 4096
#define TR 16                 // output rows per tile
#define TC 256                // cols per tile
#define HR (TR + 2)           // staged rows (with vertical halo)
#define LSTRIDE 264           // LDS row stride in floats (256 + 8 pad)
#define COL_L 260             // LDS col holding left halo scalar
#define COL_R 261             // LDS col holding right halo scalar

typedef float float4v __attribute__((ext_vector_type(4)));

__device__ __forceinline__ void row_to_lds(const float* gsrc_lane, float* lds_row_base) {
    // lane i: 16B from gsrc_lane (per-lane addr) -> lds_row_base + i*16 (linear)
    __builtin_amdgcn_global_load_lds(
        (const __attribute__((address_space(1))) uint32_t*)gsrc_lane,
        (__attribute__((address_space(3))) uint32_t*)lds_row_base,
        16, 0, 0);
}

__global__ __launch_bounds__(256, 8) void flux_stencil_kernel(
    const float* __restrict__ u,
    const float* __restrict__ D_eff,
    const float* __restrict__ dv,
    const float* __restrict__ st,
    float* __restrict__ out)
{
    __shared__ float s[HR * LSTRIDE];

    const float D  = D_eff[0];
    const float s0 = st[0];
    const float s1 = st[1];
    const float k1 = D * s0;         // neighbor coefficient
    const float k4 = 4.0f * D * s1;  // center coefficient
    const float dvUp = dv[0], dvDn = dv[1], dvL = dv[2], dvR = dv[3];

    // XCD swizzle (XCD = b%8): XCD X gets bands [32X, 32X+32), all 16 col-tiles.
    const int b    = blockIdx.x;
    const int X    = b & 7;
    const int r    = b >> 3;               // [0,512)
    const int ct   = r & 15;               // col-tile [0,16)
    const int band = X * 32 + (r >> 4);    // [0,256)
    const int i0   = band * TR;
    const int j0   = ct * TC;

    const int t    = threadIdx.x;
    const int w    = t >> 6;               // wave [0,4)
    const int lane = t & 63;

    const bool topEdge = (i0 == 0);
    const bool botEdge = (i0 + TR == NX);

    // ---- stage interior: 18 rows, one global_load_lds dwordx4 per row ----
    // LDS row k <-> grid row (i0 + k - 1), clamped at grid ends (top/bottom
    // Dirichlet values are substituted at compute time).
    for (int k = w; k < HR; k += 4) {
        int gr = i0 + k - 1;
        gr = gr < 0 ? 0 : (gr > NX - 1 ? NX - 1 : gr);
        row_to_lds(u + (size_t)gr * NY + j0 + 4 * lane, &s[k * LSTRIDE]);
    }

    // ---- stage halo column scalars for the 16 output rows ----
    if (t < TR) {                        // wave 0: left halo
        const int k  = 1 + t;
        const int gr = i0 + k - 1;
        s[k * LSTRIDE + COL_L] = (j0 == 0) ? dvL : u[(size_t)gr * NY + j0 - 1];
    } else if (t >= 64 && t < 64 + TR) { // wave 1: right halo
        const int k  = 1 + (t - 64);
        const int gr = i0 + k - 1;
        s[k * LSTRIDE + COL_R] = (j0 + TC == NY) ? dvR : u[(size_t)gr * NY + j0 + TC];
    }

    __syncthreads();   // drains global_load_lds (vmcnt) + ds_writes (lgkm)

    // ---- compute 16 rows x 256 cols from LDS; wave w owns rows 4w+1..4w+4 ----
    #pragma unroll
    for (int rr = 0; rr < 4; ++rr) {
        const int k = 1 + w * 4 + rr;                  // LDS row index
        const float* rowc = &s[k * LSTRIDE];

        float4v up = *(const float4v*)&s[(k - 1) * LSTRIDE + 4 * lane];
        float4v c  = *(const float4v*)&rowc[4 * lane];
        float4v dn = *(const float4v*)&s[(k + 1) * LSTRIDE + 4 * lane];

        // lft/rgt via shifted b128 reads; edge lanes read the halo slot (16B-aligned)
        const float4v lv = *(const float4v*)&rowc[lane == 0  ? COL_L : 4 * lane - 4];
        const float4v rv = *(const float4v*)&rowc[lane == 63 ? COL_L : 4 * lane + 4];
        const float lft = (lane == 0)  ? lv.x : lv.w;   // COL_L holds left scalar
        const float rgt = (lane == 63) ? rv.y : rv.x;   // COL_R = COL_L+1 -> .y

        if (topEdge && k == 1)  { up.x = dvUp; up.y = dvUp; up.z = dvUp; up.w = dvUp; }
        if (botEdge && k == TR) { dn.x = dvDn; dn.y = dvDn; dn.z = dvDn; dn.w = dvDn; }

        float4v o;
        o.x = k1 * (up.x + dn.x + lft + c.y) + k4 * c.x;
        o.y = k1 * (up.y + dn.y + c.x + c.z) + k4 * c.y;
        o.z = k1 * (up.z + dn.z + c.y + c.w) + k4 * c.z;
        o.w = k1 * (up.w + dn.w + c.z + rgt) + k4 * c.w;

        *(float4v*)(out + (size_t)(i0 + k - 1) * NY + j0 + 4 * lane) = o;
    }
}

extern "C" void kernel_launch(void* const* d_in, const int* in_sizes, int n_in,
                              void* d_out, int out_size, void* d_ws, size_t ws_size,
                              hipStream_t stream) {
    const float* u_main    = (const float*)d_in[0];
    // d_in[1] = u_coupled (unused)
    const float* D_eff     = (const float*)d_in[2];
    const float* dirichlet = (const float*)d_in[3];
    const float* stencil   = (const float*)d_in[4];
    // d_in[5] = t (unused)
    float* outp = (float*)d_out;

    // 256 bands x 16 col-tiles = 4096 blocks of 256 threads
    const int grid  = 4096;
    const int block = 256;

    flux_stencil_kernel<<<grid, block, 0, stream>>>(u_main, D_eff, dirichlet, stencil, outp);
}

// Round 13
// 24.499 us; speedup vs baseline: 1.2196x; 1.0012x over previous
//
#include <hip/hip_runtime.h>
#include <cstdint>

// Flux_Kernels: 5-point stencil with Dirichlet BCs on all 4 sides.
// out[i,j] = D * ( s0*(nUp + nDown + nLeft + nRight) + 4*s1*u[i,j] )
// Off-grid neighbors -> dirichlet_val[{0,1,2,3}] for {i=0, i=NX-1, j=0, j=NY-1}.
//
// Round-13: R12 (global_load_lds DMA staging -- broke the register-path
// plateau, 26.1 -> 24.5 us) with two refinements:
//   1. TR=32 (HR=34): half the per-element barrier/stage overhead, vertical
//      read amp 1.125 -> 1.0625. LDS 36 KB -> 4 blocks/CU (16 waves/CU;
//      R11 showed extra waves don't help -- staging is block-level DMA).
//   2. Halo via two ds_read_b32 scalars (lft at 4l-1, rgt at 4l+4; both
//      2-way bank aliasing = free) instead of two shifted b128 reads:
//      LDS read traffic per output row 5 KB -> 3.1 KB.

#define NX 4096
#define NY 4096
#define TR 32                 // output rows per tile
#define TC 256                // cols per tile
#define HR (TR + 2)           // staged rows (with vertical halo)
#define LSTRIDE 264           // LDS row stride in floats (256 + 8 pad)
#define COL_L 260             // LDS col holding left halo scalar
#define COL_R 261             // LDS col holding right halo scalar

typedef float float4v __attribute__((ext_vector_type(4)));

__device__ __forceinline__ void row_to_lds(const float* gsrc_lane, float* lds_row_base) {
    // lane i: 16B from gsrc_lane (per-lane addr) -> lds_row_base + i*16 (linear)
    __builtin_amdgcn_global_load_lds(
        (const __attribute__((address_space(1))) uint32_t*)gsrc_lane,
        (__attribute__((address_space(3))) uint32_t*)lds_row_base,
        16, 0, 0);
}

__global__ __launch_bounds__(256, 4) void flux_stencil_kernel(
    const float* __restrict__ u,
    const float* __restrict__ D_eff,
    const float* __restrict__ dv,
    const float* __restrict__ st,
    float* __restrict__ out)
{
    __shared__ float s[HR * LSTRIDE];

    const float D  = D_eff[0];
    const float s0 = st[0];
    const float s1 = st[1];
    const float k1 = D * s0;         // neighbor coefficient
    const float k4 = 4.0f * D * s1;  // center coefficient
    const float dvUp = dv[0], dvDn = dv[1], dvL = dv[2], dvR = dv[3];

    // XCD swizzle (XCD = b%8): XCD X gets bands [16X, 16X+16), all 16 col-tiles.
    const int b    = blockIdx.x;               // [0,2048)
    const int X    = b & 7;
    const int r    = b >> 3;                   // [0,256)
    const int ct   = r & 15;                   // col-tile [0,16)
    const int band = X * 16 + (r >> 4);        // [0,128)
    const int i0   = band * TR;
    const int j0   = ct * TC;

    const int t    = threadIdx.x;
    const int w    = t >> 6;                   // wave [0,4)
    const int lane = t & 63;

    const bool topEdge = (i0 == 0);
    const bool botEdge = (i0 + TR == NX);

    // ---- stage interior: 34 rows, one global_load_lds dwordx4 per row ----
    // LDS row k <-> grid row (i0 + k - 1), clamped at grid ends (top/bottom
    // Dirichlet values substituted at compute time).
    for (int k = w; k < HR; k += 4) {
        int gr = i0 + k - 1;
        gr = gr < 0 ? 0 : (gr > NX - 1 ? NX - 1 : gr);
        row_to_lds(u + (size_t)gr * NY + j0 + 4 * lane, &s[k * LSTRIDE]);
    }

    // ---- stage halo column scalars for the 32 output rows ----
    if (t < TR) {                        // wave 0: left halo
        const int k  = 1 + t;
        const int gr = i0 + k - 1;
        s[k * LSTRIDE + COL_L] = (j0 == 0) ? dvL : u[(size_t)gr * NY + j0 - 1];
    } else if (t >= 64 && t < 64 + TR) { // wave 1: right halo
        const int k  = 1 + (t - 64);
        const int gr = i0 + k - 1;
        s[k * LSTRIDE + COL_R] = (j0 + TC == NY) ? dvR : u[(size_t)gr * NY + j0 + TC];
    }

    __syncthreads();   // drains global_load_lds (vmcnt) + ds_writes (lgkm)

    // ---- compute 32 rows x 256 cols from LDS; wave w owns rows 8w+1..8w+8 ----
    #pragma unroll
    for (int rr = 0; rr < 8; ++rr) {
        const int k = 1 + w * 8 + rr;                  // LDS row index
        const float* rowc = &s[k * LSTRIDE];

        float4v up = *(const float4v*)&s[(k - 1) * LSTRIDE + 4 * lane];
        float4v c  = *(const float4v*)&rowc[4 * lane];
        float4v dn = *(const float4v*)&s[(k + 1) * LSTRIDE + 4 * lane];

        // halo scalars: ds_read_b32 (2-way bank aliasing = free)
        const float lft = rowc[lane == 0  ? COL_L : 4 * lane - 1];
        const float rgt = rowc[lane == 63 ? COL_R : 4 * lane + 4];

        if (topEdge && k == 1)  { up.x = dvUp; up.y = dvUp; up.z = dvUp; up.w = dvUp; }
        if (botEdge && k == TR) { dn.x = dvDn; dn.y = dvDn; dn.z = dvDn; dn.w = dvDn; }

        float4v o;
        o.x = k1 * (up.x + dn.x + lft + c.y) + k4 * c.x;
        o.y = k1 * (up.y + dn.y + c.x + c.z) + k4 * c.y;
        o.z = k1 * (up.z + dn.z + c.y + c.w) + k4 * c.z;
        o.w = k1 * (up.w + dn.w + c.z + rgt) + k4 * c.w;

        *(float4v*)(out + (size_t)(i0 + k - 1) * NY + j0 + 4 * lane) = o;
    }
}

extern "C" void kernel_launch(void* const* d_in, const int* in_sizes, int n_in,
                              void* d_out, int out_size, void* d_ws, size_t ws_size,
                              hipStream_t stream) {
    const float* u_main    = (const float*)d_in[0];
    // d_in[1] = u_coupled (unused)
    const float* D_eff     = (const float*)d_in[2];
    const float* dirichlet = (const float*)d_in[3];
    const float* stencil   = (const float*)d_in[4];
    // d_in[5] = t (unused)
    float* outp = (float*)d_out;

    // 128 bands x 16 col-tiles = 2048 blocks of 256 threads
    const int grid  = 2048;
    const int block = 256;

    flux_stencil_kernel<<<grid, block, 0, stream>>>(u_main, D_eff, dirichlet, stencil, outp);
}

// Round 14
// 24.294 us; speedup vs baseline: 1.2299x; 1.0084x over previous
//
#include <hip/hip_runtime.h>
#include <cstdint>

// Flux_Kernels: 5-point stencil with Dirichlet BCs on all 4 sides.
// out[i,j] = D * ( s0*(nUp + nDown + nLeft + nRight) + 4*s1*u[i,j] )
// Off-grid neighbors -> dirichlet_val[{0,1,2,3}] for {i=0, i=NX-1, j=0, j=NY-1}.
//
// Round-14: R13's TR=32 global_load_lds staging, compute phase restructured:
//   1. Halo via R12's shifted ds_read_b128 (conflict-free) -- R13's b32 halo
//      at stride 16B was an 8-WAY bank conflict (815K conflict cycles), which
//      ate the TR=32 staging gain (FETCH did drop 38.6->33.1 MB as predicted).
//   2. Rolling vertical reuse: wave w owns 8 consecutive rows, so up/c of
//      row k+1 are c/dn of row k. Roll (c,lft,rgt) <- (dn,dnl,dnr): only
//      3 conflict-free b128 reads per output row (R12 used 5, R13 3+2conf).

#define NX 4096
#define NY 4096
#define TR 32                 // output rows per tile
#define TC 256                // cols per tile
#define HR (TR + 2)           // staged rows (with vertical halo)
#define LSTRIDE 264           // LDS row stride in floats (256 + 8 pad)
#define COL_L 260             // left halo scalar (260*4=1040, 16B-aligned)
#define COL_R 261             // right halo scalar (= COL_L + 1)

typedef float float4v __attribute__((ext_vector_type(4)));

__device__ __forceinline__ void row_to_lds(const float* gsrc_lane, float* lds_row_base) {
    // lane i: 16B from gsrc_lane (per-lane addr) -> lds_row_base + i*16 (linear)
    __builtin_amdgcn_global_load_lds(
        (const __attribute__((address_space(1))) uint32_t*)gsrc_lane,
        (__attribute__((address_space(3))) uint32_t*)lds_row_base,
        16, 0, 0);
}

__global__ __launch_bounds__(256, 4) void flux_stencil_kernel(
    const float* __restrict__ u,
    const float* __restrict__ D_eff,
    const float* __restrict__ dv,
    const float* __restrict__ st,
    float* __restrict__ out)
{
    __shared__ float s[HR * LSTRIDE];

    const float D  = D_eff[0];
    const float s0 = st[0];
    const float s1 = st[1];
    const float k1 = D * s0;         // neighbor coefficient
    const float k4 = 4.0f * D * s1;  // center coefficient
    const float dvUp = dv[0], dvDn = dv[1], dvL = dv[2], dvR = dv[3];

    // XCD swizzle (XCD = b%8): XCD X gets bands [16X, 16X+16), all 16 col-tiles.
    const int b    = blockIdx.x;               // [0,2048)
    const int X    = b & 7;
    const int r    = b >> 3;                   // [0,256)
    const int ct   = r & 15;                   // col-tile [0,16)
    const int band = X * 16 + (r >> 4);        // [0,128)
    const int i0   = band * TR;
    const int j0   = ct * TC;

    const int t    = threadIdx.x;
    const int w    = t >> 6;                   // wave [0,4)
    const int lane = t & 63;

    const bool topEdge = (i0 == 0);
    const bool botEdge = (i0 + TR == NX);

    // ---- stage interior: 34 rows, one global_load_lds dwordx4 per row ----
    for (int k = w; k < HR; k += 4) {
        int gr = i0 + k - 1;
        gr = gr < 0 ? 0 : (gr > NX - 1 ? NX - 1 : gr);
        row_to_lds(u + (size_t)gr * NY + j0 + 4 * lane, &s[k * LSTRIDE]);
    }

    // ---- stage halo column scalars for the 32 output rows ----
    if (t < TR) {                        // wave 0: left halo
        const int k  = 1 + t;
        const int gr = i0 + k - 1;
        s[k * LSTRIDE + COL_L] = (j0 == 0) ? dvL : u[(size_t)gr * NY + j0 - 1];
    } else if (t >= 64 && t < 64 + TR) { // wave 1: right halo
        const int k  = 1 + (t - 64);
        const int gr = i0 + k - 1;
        s[k * LSTRIDE + COL_R] = (j0 + TC == NY) ? dvR : u[(size_t)gr * NY + j0 + TC];
    }

    __syncthreads();   // drains global_load_lds (vmcnt) + ds_writes (lgkm)

    // ---- compute: wave w owns rows 8w+1..8w+8 (LDS row index k) ----
    // Rolling state: up/c are registers; per row read only {dn, dnl, dnr}.
    const int kBase  = 1 + w * 8;
    const int cOff   = 4 * lane;                           // aligned b128 offset
    const int lOff   = (lane == 0)  ? COL_L : 4 * lane - 4; // shifted-left b128
    const int rOff   = (lane == 63) ? COL_L : 4 * lane + 4; // shifted-right b128

    // prologue: up = row kBase-1 (aligned), c/lft/rgt = row kBase
    float4v up = *(const float4v*)&s[(kBase - 1) * LSTRIDE + cOff];
    float4v c  = *(const float4v*)&s[kBase * LSTRIDE + cOff];
    {
        const float4v lv = *(const float4v*)&s[kBase * LSTRIDE + lOff];
        const float4v rv = *(const float4v*)&s[kBase * LSTRIDE + rOff];
        // store rolled halo in registers
        float lft = (lane == 0)  ? lv.x : lv.w;
        float rgt = (lane == 63) ? rv.y : rv.x;

        if (topEdge && w == 0) { up.x = dvUp; up.y = dvUp; up.z = dvUp; up.w = dvUp; }

        #pragma unroll
        for (int rr = 0; rr < 8; ++rr) {
            const int k = kBase + rr;              // current row's LDS index
            const float* nrow = &s[(k + 1) * LSTRIDE];

            // next row's data (becomes c/lft/rgt after compute)
            float4v dn  = *(const float4v*)&nrow[cOff];
            const float4v dnl = *(const float4v*)&nrow[lOff];
            const float4v dnr = *(const float4v*)&nrow[rOff];

            if (botEdge && k == TR) { dn.x = dvDn; dn.y = dvDn; dn.z = dvDn; dn.w = dvDn; }

            float4v o;
            o.x = k1 * (up.x + dn.x + lft + c.y) + k4 * c.x;
            o.y = k1 * (up.y + dn.y + c.x + c.z) + k4 * c.y;
            o.z = k1 * (up.z + dn.z + c.y + c.w) + k4 * c.z;
            o.w = k1 * (up.w + dn.w + c.z + rgt) + k4 * c.w;

            *(float4v*)(out + (size_t)(i0 + k - 1) * NY + j0 + cOff) = o;

            up  = c;
            c   = dn;
            lft = (lane == 0)  ? dnl.x : dnl.w;
            rgt = (lane == 63) ? dnr.y : dnr.x;
        }
    }
}

extern "C" void kernel_launch(void* const* d_in, const int* in_sizes, int n_in,
                              void* d_out, int out_size, void* d_ws, size_t ws_size,
                              hipStream_t stream) {
    const float* u_main    = (const float*)d_in[0];
    // d_in[1] = u_coupled (unused)
    const float* D_eff     = (const float*)d_in[2];
    const float* dirichlet = (const float*)d_in[3];
    const float* stencil   = (const float*)d_in[4];
    // d_in[5] = t (unused)
    float* outp = (float*)d_out;

    // 128 bands x 16 col-tiles = 2048 blocks of 256 threads
    const int grid  = 2048;
    const int block = 256;

    flux_stencil_kernel<<<grid, block, 0, stream>>>(u_main, D_eff, dirichlet, stencil, outp);
}